// Round 2
// baseline (468.598 us; speedup 1.0000x reference)
//
#include <hip/hip_runtime.h>

typedef __bf16 bf16x8 __attribute__((ext_vector_type(8)));
typedef float f32x4 __attribute__((ext_vector_type(4)));
typedef unsigned short us8 __attribute__((ext_vector_type(8)));

#define PI_F 3.14159265358979323846f

__device__ __forceinline__ unsigned short f2bf(float f) {
    unsigned u = __float_as_uint(f);
    u += 0x7FFFu + ((u >> 16) & 1u);   // RNE
    return (unsigned short)(u >> 16);
}
__device__ __forceinline__ float bf2f(unsigned short h) {
    return __uint_as_float(((unsigned)h) << 16);
}

__device__ __forceinline__ void async16(const void* g, void* l) {
    __builtin_amdgcn_global_load_lds(
        (const __attribute__((address_space(1))) unsigned int*)g,
        (__attribute__((address_space(3))) unsigned int*)l, 16, 0, 0);
}

// ---------------------------------------------------------------------------
// Merged weight prep.
// idx < 1M : W1b[(k*8+h)*1024 + d] = bf16( W_proj[h,k,d] * cos(pi*freq[h,k]) )
// else     : Wob[n*1024 + (k*8+h)] = bf16( out_W[n, h*128+k] )
__global__ __launch_bounds__(256) void prep_k(const float* __restrict__ W,
                                              const float* __restrict__ fr,
                                              const float* __restrict__ Wo,
                                              unsigned short* __restrict__ W1b,
                                              unsigned short* __restrict__ Wob) {
    int idx = blockIdx.x * 256 + threadIdx.x;      // 2M
    if (idx < (1 << 20)) {
        int n = idx >> 10, d = idx & 1023;
        int k = n >> 3, h = n & 7;
        float c = cosf(fr[h * 128 + k] * PI_F);
        W1b[idx] = f2bf(W[((h * 128 + k) << 10) + d] * c);
    } else {
        int i2 = idx - (1 << 20);
        int n = i2 >> 10, dp = i2 & 1023;
        int k = dp >> 3, h = dp & 7;
        Wob[i2] = f2bf(Wo[(n << 10) + h * 128 + k]);
    }
}

// ---------------------------------------------------------------------------
// x -> bf16 cast + per-(b,d) column sums (for summary). xbar pre-zeroed.
__global__ __launch_bounds__(256) void xbar_cast(const float* __restrict__ x,
                                                 unsigned short* __restrict__ xb,
                                                 float* __restrict__ xbar) {
    int bid = blockIdx.x;            // 512
    int b = bid >> 7;
    int s0 = (bid & 127) * 32;
    int t = threadIdx.x;             // d4 index
    float a0 = 0.f, a1 = 0.f, a2 = 0.f, a3 = 0.f;
    for (int i = 0; i < 32; ++i) {
        long row = (long)b * 4096 + s0 + i;
        float4 v = ((const float4*)x)[row * 256 + t];
        a0 += v.x; a1 += v.y; a2 += v.z; a3 += v.w;
        ushort4 u;
        u.x = f2bf(v.x); u.y = f2bf(v.y); u.z = f2bf(v.z); u.w = f2bf(v.w);
        ((ushort4*)xb)[row * 256 + t] = u;
    }
    float* xr = xbar + b * 1024 + t * 4;
    atomicAdd(xr + 0, a0); atomicAdd(xr + 1, a1);
    atomicAdd(xr + 2, a2); atomicAdd(xr + 3, a3);
}

// ---------------------------------------------------------------------------
// Per-(b,h) block: summary[k] = (1/S)*cos(pi*fr)*dot(xbar[b,:], W[h,k,:]),
// then pol[b,h,p] = tanh(sum_k summary[k]*pol_W[h,p,k] + pol_b[h,p]).
__global__ __launch_bounds__(256) void sumpol_k(const float* __restrict__ xbar,
                                                const float* __restrict__ W,
                                                const float* __restrict__ fr,
                                                const float* __restrict__ pol_W,
                                                const float* __restrict__ pol_b,
                                                float* __restrict__ pol_g) {
    __shared__ float summ_s[128];
    int blk = blockIdx.x;            // 32 = b*8 + h
    int b = blk >> 3, h = blk & 7;
    int t = threadIdx.x;
    int wave = t >> 6, lane = t & 63;
    const float* xrow = &xbar[b << 10];
    for (int k = wave; k < 128; k += 4) {
        const float* wrow = &W[(h * 128 + k) << 10];
        float s = 0.f;
        for (int d = lane; d < 1024; d += 64) s += xrow[d] * wrow[d];
        for (int off = 32; off; off >>= 1) s += __shfl_down(s, off);
        if (lane == 0) {
            float c = cosf(fr[h * 128 + k] * PI_F);
            summ_s[k] = s * c * (1.0f / 4096.0f);
        }
    }
    __syncthreads();
    int p = t >> 3, sl = t & 7;      // 32 p-outputs, 8 lanes each
    const float* prow = &pol_W[(h * 32 + p) * 128];
    float s = 0.f;
    for (int i = 0; i < 16; ++i) {
        int k = sl * 16 + i;
        s += summ_s[k] * prow[k];
    }
    s += __shfl_down(s, 4);
    s += __shfl_down(s, 2);
    s += __shfl_down(s, 1);
    if (sl == 0)
        pol_g[(b * 8 + h) * 32 + p] = tanhf(s + pol_b[h * 32 + p]);
}

// ---------------------------------------------------------------------------
// normalize pol -> dots -> gelu MLP -> softplus -> impedance & coef. 1 block.
__global__ __launch_bounds__(256) void imp2_k(const float* __restrict__ pol_g,
                                              const float* __restrict__ imp_W1,
                                              const float* __restrict__ imp_b1,
                                              const float* __restrict__ imp_W2,
                                              const float* __restrict__ imp_b2,
                                              float* __restrict__ coef_out,
                                              float* __restrict__ imp_out) {
    __shared__ float pol[1024];      // [b][h][p]
    __shared__ float rn[32];
    int t = threadIdx.x;
    for (int o = t; o < 1024; o += 256) pol[o] = pol_g[o];
    __syncthreads();
    if (t < 32) {
        float ss = 0.f;
        for (int p = 0; p < 32; ++p) { float v = pol[t * 32 + p]; ss += v * v; }
        rn[t] = 1.0f / fmaxf(sqrtf(ss), 1e-12f);
    }
    __syncthreads();
    {
        int b = t >> 6, i = (t >> 3) & 7, j = t & 7;
        float d = 0.f;
        for (int p = 0; p < 32; ++p)
            d += pol[(b * 8 + i) * 32 + p] * pol[(b * 8 + j) * 32 + p];
        d *= rn[b * 8 + i] * rn[b * 8 + j];
        float s = imp_b2[0];
        for (int c = 0; c < 16; ++c) {
            float z = d * imp_W1[c] + imp_b1[c];
            float gl = 0.5f * z * (1.0f + erff(z * 0.70710678118654752f));
            s += gl * imp_W2[c];
        }
        float sp = fmaxf(s, 0.0f) + log1pf(expf(-fabsf(s)));   // softplus
        float impv = (i == j) ? 0.0f : sp;
        imp_out[t] = impv;
        coef_out[t] = (i == j) ? 0.0f : 0.1f / (1.0f + impv);
    }
}

// ---------------------------------------------------------------------------
// XCD-aware block remap: each XCD (n&7) gets a contiguous 16-row-band slab,
// iterating cols slowest so its A slab + full B stay L2-resident.
__device__ __forceinline__ void swizzle_blk(int n, long& rowBase, long& colBase) {
    int xcd = n & 7, s = n >> 3;
    rowBase = (long)(xcd * 16 + (s & 15)) * 128;
    colBase = (long)(s >> 4) * 128;
}

// GEMM1 + fused head-mix epilogue.
// C[M=16384, N=1024] = A @ B^T (bf16, fp32 acc); columns are (k,h)-interleaved
// so each 8-col group is one k's 8 heads; epilogue applies
// out[i] = v[i] + scale_s * sum_j coef[b,i,j]*v[j] via LDS round-trip.
__global__ __launch_bounds__(256, 3) void gemm1_mix(const unsigned short* __restrict__ A,
                                                    const unsigned short* __restrict__ B,
                                                    const float* __restrict__ coef,
                                                    const int* __restrict__ causal,
                                                    unsigned short* __restrict__ C) {
    __shared__ float mixs[64 * 132];             // 33792 B, aliased As/Bs
    __shared__ float cfs[64];
    unsigned short* As = (unsigned short*)mixs;  // 8 KB
    unsigned short* Bs = As + 4096;              // 8 KB
    const int t = threadIdx.x;
    const int wave = t >> 6;
    const int lane = t & 63;
    const int wr = wave >> 1, wc = wave & 1;
    long rowBase, colBase;
    swizzle_blk(blockIdx.x, rowBase, colBase);
    const int b = (int)(rowBase >> 12);
    if (t < 64) cfs[t] = coef[b * 64 + t];
    const int causalv = causal[0];

    const int lr = lane >> 2;
    const int lb = (lane & 3) * 16;
    const char* gA = (const char*)A + (rowBase + wave * 32 + lr) * 2048 + lb;
    const char* gB = (const char*)B + (colBase + wave * 32 + lr) * 2048 + lb;
    char* lA = (char*)As + wave * 2048;
    char* lB = (char*)Bs + wave * 2048;
    const int q = lane >> 4;
    const int c16 = lane & 15;

    f32x4 acc[4][4] = {};
    for (int kt = 0; kt < 1024; kt += 32) {
        const char* a0 = gA + kt * 2;
        const char* b0 = gB + kt * 2;
        async16(a0, lA);
        async16(a0 + 16 * 2048, lA + 1024);
        async16(b0, lB);
        async16(b0 + 16 * 2048, lB + 1024);
        __syncthreads();
        bf16x8 af[4], bfr[4];
#pragma unroll
        for (int mi = 0; mi < 4; ++mi)
            af[mi] = *(const bf16x8*)((const char*)As + ((wr * 64 + mi * 16 + c16) * 32 + q * 8) * 2);
#pragma unroll
        for (int ni = 0; ni < 4; ++ni)
            bfr[ni] = *(const bf16x8*)((const char*)Bs + ((wc * 64 + ni * 16 + c16) * 32 + q * 8) * 2);
#pragma unroll
        for (int mi = 0; mi < 4; ++mi)
#pragma unroll
            for (int ni = 0; ni < 4; ++ni)
                acc[mi][ni] = __builtin_amdgcn_mfma_f32_16x16x32_bf16(af[mi], bfr[ni], acc[mi][ni], 0, 0, 0);
        __syncthreads();
    }

    // Epilogue: two 64-row passes through LDS, mix 8 heads per k-group.
#pragma unroll
    for (int pass = 0; pass < 2; ++pass) {
        if (wr == pass) {
#pragma unroll
            for (int mi = 0; mi < 4; ++mi)
#pragma unroll
                for (int ni = 0; ni < 4; ++ni)
#pragma unroll
                    for (int r = 0; r < 4; ++r)
                        mixs[(mi * 16 + q * 4 + r) * 132 + wc * 64 + ni * 16 + c16] = acc[mi][ni][r];
        }
        __syncthreads();
        long rb2 = rowBase + pass * 64;
#pragma unroll
        for (int it = 0; it < 4; ++it) {
            int item = t + it * 256;             // 1024 = 64 rows x 16 kgroups
            int r = item >> 4, kg = item & 15;
            const float* src = mixs + r * 132 + kg * 8;
            float v[8];
#pragma unroll
            for (int j = 0; j < 8; ++j) v[j] = src[j];
            long row = rb2 + r;
            float scale = causalv ? (float)((row & 4095) + 1) * (1.0f / 4096.0f) : 1.0f;
            us8 o;
#pragma unroll
            for (int i = 0; i < 8; ++i) {
                float ts = 0.f;
#pragma unroll
                for (int j = 0; j < 8; ++j) ts += cfs[i * 8 + j] * v[j];
                o[i] = f2bf(v[i] + scale * ts);
            }
            *(us8*)(C + row * 1024 + colBase + kg * 8) = o;
        }
        __syncthreads();
    }
}

// ---------------------------------------------------------------------------
// Plain GEMM (second projection): C = A @ B^T, bf16 out.
__global__ __launch_bounds__(256, 3) void gemm_bt(const unsigned short* __restrict__ A,
                                                  const unsigned short* __restrict__ B,
                                                  unsigned short* __restrict__ C) {
    __shared__ unsigned short As[128 * 32];
    __shared__ unsigned short Bs[128 * 32];
    const int t = threadIdx.x;
    const int wave = t >> 6;
    const int lane = t & 63;
    const int wr = wave >> 1, wc = wave & 1;
    long rowBase, colBase;
    swizzle_blk(blockIdx.x, rowBase, colBase);

    const int lr = lane >> 2;
    const int lb = (lane & 3) * 16;
    const char* gA = (const char*)A + (rowBase + wave * 32 + lr) * 2048 + lb;
    const char* gB = (const char*)B + (colBase + wave * 32 + lr) * 2048 + lb;
    char* lA = (char*)As + wave * 2048;
    char* lB = (char*)Bs + wave * 2048;
    const int q = lane >> 4;
    const int c16 = lane & 15;

    f32x4 acc[4][4] = {};
    for (int kt = 0; kt < 1024; kt += 32) {
        const char* a0 = gA + kt * 2;
        const char* b0 = gB + kt * 2;
        async16(a0, lA);
        async16(a0 + 16 * 2048, lA + 1024);
        async16(b0, lB);
        async16(b0 + 16 * 2048, lB + 1024);
        __syncthreads();
        bf16x8 af[4], bfr[4];
#pragma unroll
        for (int mi = 0; mi < 4; ++mi)
            af[mi] = *(const bf16x8*)((const char*)As + ((wr * 64 + mi * 16 + c16) * 32 + q * 8) * 2);
#pragma unroll
        for (int ni = 0; ni < 4; ++ni)
            bfr[ni] = *(const bf16x8*)((const char*)Bs + ((wc * 64 + ni * 16 + c16) * 32 + q * 8) * 2);
#pragma unroll
        for (int mi = 0; mi < 4; ++mi)
#pragma unroll
            for (int ni = 0; ni < 4; ++ni)
                acc[mi][ni] = __builtin_amdgcn_mfma_f32_16x16x32_bf16(af[mi], bfr[ni], acc[mi][ni], 0, 0, 0);
        __syncthreads();
    }
#pragma unroll
    for (int mi = 0; mi < 4; ++mi) {
#pragma unroll
        for (int ni = 0; ni < 4; ++ni) {
            long col = colBase + wc * 64 + ni * 16 + c16;
            long row0 = rowBase + wr * 64 + mi * 16 + q * 4;
#pragma unroll
            for (int r = 0; r < 4; ++r)
                C[(row0 + r) * 1024 + col] = f2bf(acc[mi][ni][r]);
        }
    }
}

// ---------------------------------------------------------------------------
// LayerNorm over D=1024: y = ypre + out_b + x; out = (y-mu)/sqrt(var+eps)*g+b
__global__ __launch_bounds__(256) void ln_k(const unsigned short* __restrict__ ypre,
                                            const float* __restrict__ x,
                                            const float* __restrict__ outb,
                                            const float* __restrict__ gam,
                                            const float* __restrict__ bet,
                                            float* __restrict__ out) {
    int row = blockIdx.x;       // 16384
    int t = threadIdx.x;        // 256, 4 elems each
    long base = (long)row * 1024 + t * 4;
    ushort4 yp = *(const ushort4*)(ypre + base);
    float4 xv = *(const float4*)(x + base);
    float4 bv = *(const float4*)(outb + t * 4);
    float y0 = bf2f(yp.x) + xv.x + bv.x;
    float y1 = bf2f(yp.y) + xv.y + bv.y;
    float y2 = bf2f(yp.z) + xv.z + bv.z;
    float y3 = bf2f(yp.w) + xv.w + bv.w;
    float s = y0 + y1 + y2 + y3;
    float ss = y0 * y0 + y1 * y1 + y2 * y2 + y3 * y3;
    for (int off = 32; off; off >>= 1) {
        s += __shfl_down(s, off);
        ss += __shfl_down(ss, off);
    }
    __shared__ float red[8];
    int wv = t >> 6, ln = t & 63;
    if (ln == 0) { red[wv] = s; red[4 + wv] = ss; }
    __syncthreads();
    if (t == 0) {
        float S1 = red[0] + red[1] + red[2] + red[3];
        float S2 = red[4] + red[5] + red[6] + red[7];
        float mu = S1 * (1.0f / 1024.0f);
        float var = S2 * (1.0f / 1024.0f) - mu * mu;
        red[0] = mu;
        red[1] = 1.0f / sqrtf(var + 1e-5f);
    }
    __syncthreads();
    float mu = red[0], rs = red[1];
    float4 gv = *(const float4*)(gam + t * 4);
    float4 bb = *(const float4*)(bet + t * 4);
    float4 o;
    o.x = (y0 - mu) * rs * gv.x + bb.x;
    o.y = (y1 - mu) * rs * gv.y + bb.y;
    o.z = (y2 - mu) * rs * gv.z + bb.z;
    o.w = (y3 - mu) * rs * gv.w + bb.w;
    *(float4*)(out + base) = o;
}

// ---------------------------------------------------------------------------
extern "C" void kernel_launch(void* const* d_in, const int* in_sizes, int n_in,
                              void* d_out, int out_size, void* d_ws, size_t ws_size,
                              hipStream_t stream) {
    const float* x       = (const float*)d_in[0];
    const float* W_proj  = (const float*)d_in[1];
    const float* freqs   = (const float*)d_in[2];
    const float* pol_W   = (const float*)d_in[3];
    const float* pol_b   = (const float*)d_in[4];
    const float* imp_W1  = (const float*)d_in[5];
    const float* imp_b1  = (const float*)d_in[6];
    const float* imp_W2  = (const float*)d_in[7];
    const float* imp_b2  = (const float*)d_in[8];
    const float* out_W   = (const float*)d_in[9];
    const float* out_b   = (const float*)d_in[10];
    const float* ln_g    = (const float*)d_in[11];
    const float* ln_b    = (const float*)d_in[12];
    const int*   causal  = (const int*)d_in[13];
    float* out = (float*)d_out;

    char* ws = (char*)d_ws;
    unsigned short* xb      = (unsigned short*)(ws + 0);          // 32MB, dead after gemm1 -> reused as ypre
    unsigned short* merged  = (unsigned short*)(ws + 33554432);   // 32MB
    unsigned short* w1b     = (unsigned short*)(ws + 67108864);   // 2MB
    unsigned short* wob     = (unsigned short*)(ws + 69206016);   // 2MB
    float* xbar             = (float*)(ws + 71303168);            // 16KB
    float* pol_g            = (float*)(ws + 71319552);            // 4KB
    float* coef             = (float*)(ws + 71323648);            // 1KB
    unsigned short* ypre    = xb;

    hipMemsetAsync(xbar, 0, 4096 * sizeof(float), stream);
    prep_k<<<8192, 256, 0, stream>>>(W_proj, freqs, out_W, w1b, wob);
    xbar_cast<<<512, 256, 0, stream>>>(x, xb, xbar);
    sumpol_k<<<32, 256, 0, stream>>>(xbar, W_proj, freqs, pol_W, pol_b, pol_g);
    imp2_k<<<1, 256, 0, stream>>>(pol_g, imp_W1, imp_b1, imp_W2, imp_b2,
                                  coef, out + 16777216);
    gemm1_mix<<<1024, 256, 0, stream>>>(xb, w1b, coef, causal, merged);
    gemm_bt<<<1024, 256, 0, stream>>>(merged, wob, ypre);
    ln_k<<<16384, 256, 0, stream>>>(ypre, x, out_b, ln_g, ln_b, out);
}

// Round 3
// 403.220 us; speedup vs baseline: 1.1621x; 1.1621x over previous
//
#include <hip/hip_runtime.h>

typedef __bf16 bf16x8 __attribute__((ext_vector_type(8)));
typedef float f32x4 __attribute__((ext_vector_type(4)));
typedef unsigned short us8 __attribute__((ext_vector_type(8)));

#define PI_F 3.14159265358979323846f

__device__ __forceinline__ unsigned short f2bf(float f) {
    unsigned u = __float_as_uint(f);
    u += 0x7FFFu + ((u >> 16) & 1u);   // RNE
    return (unsigned short)(u >> 16);
}
__device__ __forceinline__ float bf2f(unsigned short h) {
    return __uint_as_float(((unsigned)h) << 16);
}

__device__ __forceinline__ void async16(const void* g, void* l) {
    __builtin_amdgcn_global_load_lds(
        (const __attribute__((address_space(1))) unsigned int*)g,
        (__attribute__((address_space(3))) unsigned int*)l, 16, 0, 0);
}

// ---------------------------------------------------------------------------
// Merged weight prep.
// idx < 1M : W1b[(k*8+h)*1024 + d] = bf16( W_proj[h,k,d] * cos(pi*freq[h,k]) )
// else     : Wob[n*1024 + (k*8+h)] = bf16( out_W[n, h*128+k] )
__global__ __launch_bounds__(256) void prep_k(const float* __restrict__ W,
                                              const float* __restrict__ fr,
                                              const float* __restrict__ Wo,
                                              unsigned short* __restrict__ W1b,
                                              unsigned short* __restrict__ Wob) {
    int idx = blockIdx.x * 256 + threadIdx.x;      // 2M
    if (idx < (1 << 20)) {
        int n = idx >> 10, d = idx & 1023;
        int k = n >> 3, h = n & 7;
        float c = cosf(fr[h * 128 + k] * PI_F);
        W1b[idx] = f2bf(W[((h * 128 + k) << 10) + d] * c);
    } else {
        int i2 = idx - (1 << 20);
        int n = i2 >> 10, dp = i2 & 1023;
        int k = dp >> 3, h = dp & 7;
        Wob[i2] = f2bf(Wo[(n << 10) + h * 128 + k]);
    }
}

// ---------------------------------------------------------------------------
// x -> bf16 cast + per-(b,d) column sums (for summary). xbar pre-zeroed.
// 2048 blocks x 8 rows for occupancy (512x32 was 2 blocks/CU).
__global__ __launch_bounds__(256) void xbar_cast(const float* __restrict__ x,
                                                 unsigned short* __restrict__ xb,
                                                 float* __restrict__ xbar) {
    int bid = blockIdx.x;            // 2048
    int b = bid >> 9;
    int s0 = (bid & 511) * 8;
    int t = threadIdx.x;             // d4 index
    float a0 = 0.f, a1 = 0.f, a2 = 0.f, a3 = 0.f;
    for (int i = 0; i < 8; ++i) {
        long row = (long)b * 4096 + s0 + i;
        float4 v = ((const float4*)x)[row * 256 + t];
        a0 += v.x; a1 += v.y; a2 += v.z; a3 += v.w;
        ushort4 u;
        u.x = f2bf(v.x); u.y = f2bf(v.y); u.z = f2bf(v.z); u.w = f2bf(v.w);
        ((ushort4*)xb)[row * 256 + t] = u;
    }
    float* xr = xbar + b * 1024 + t * 4;
    atomicAdd(xr + 0, a0); atomicAdd(xr + 1, a1);
    atomicAdd(xr + 2, a2); atomicAdd(xr + 3, a3);
}

// ---------------------------------------------------------------------------
// summary[b,h,k] = (1/S) * dot(xbar[b,:], W_proj[h,k,:]) * cos(pi*freq[h,k])
// one wave per output (round-1 proven; 32-block version was latency-bound).
__global__ __launch_bounds__(256) void summary_k(const float* __restrict__ xbar,
                                                 const float* __restrict__ W,
                                                 const float* __restrict__ fr,
                                                 float* __restrict__ summary) {
    int wave = (blockIdx.x * 256 + threadIdx.x) >> 6;   // 0..4095 = b*1024+h*128+k
    int lane = threadIdx.x & 63;
    int b = wave >> 10, hk = wave & 1023;
    int h = hk >> 7, k = hk & 127;
    const float* wrow = &W[(h * 128 + k) << 10];
    const float* xrow = &xbar[b << 10];
    float s = 0.f;
    for (int d = lane; d < 1024; d += 64) s += xrow[d] * wrow[d];
    for (int off = 32; off; off >>= 1) s += __shfl_down(s, off);
    if (lane == 0) {
        float c = cosf(fr[h * 128 + k] * PI_F);
        summary[wave] = s * c * (1.0f / 4096.0f);
    }
}

// ---------------------------------------------------------------------------
// pol -> normalize -> dots -> gelu MLP -> softplus -> impedance & coef. 1 block.
__global__ __launch_bounds__(256) void imp_k(const float* __restrict__ summary,
                                             const float* __restrict__ pol_W,
                                             const float* __restrict__ pol_b,
                                             const float* __restrict__ imp_W1,
                                             const float* __restrict__ imp_b1,
                                             const float* __restrict__ imp_W2,
                                             const float* __restrict__ imp_b2,
                                             float* __restrict__ coef_out,
                                             float* __restrict__ imp_out) {
    __shared__ float pol[4][8][32];
    __shared__ float rn[32];
    int t = threadIdx.x;
    for (int o = t; o < 1024; o += 256) {
        int b = o >> 8, h = (o >> 5) & 7, p = o & 31;
        const float* srow = &summary[(b * 8 + h) * 128];
        const float* wrow = &pol_W[(h * 32 + p) * 128];
        float acc = pol_b[h * 32 + p];
        for (int k = 0; k < 128; ++k) acc += srow[k] * wrow[k];
        pol[b][h][p] = tanhf(acc);
    }
    __syncthreads();
    if (t < 32) {
        int b = t >> 3, h = t & 7;
        float ss = 0.f;
        for (int p = 0; p < 32; ++p) { float v = pol[b][h][p]; ss += v * v; }
        rn[t] = 1.0f / fmaxf(sqrtf(ss), 1e-12f);
    }
    __syncthreads();
    {
        int b = t >> 6, i = (t >> 3) & 7, j = t & 7;
        float d = 0.f;
        for (int p = 0; p < 32; ++p) d += pol[b][i][p] * pol[b][j][p];
        d *= rn[b * 8 + i] * rn[b * 8 + j];
        float s = imp_b2[0];
        for (int c = 0; c < 16; ++c) {
            float z = d * imp_W1[c] + imp_b1[c];
            float gl = 0.5f * z * (1.0f + erff(z * 0.70710678118654752f));
            s += gl * imp_W2[c];
        }
        float sp = fmaxf(s, 0.0f) + log1pf(expf(-fabsf(s)));   // softplus
        float impv = (i == j) ? 0.0f : sp;
        imp_out[t] = impv;
        coef_out[t] = (i == j) ? 0.0f : 0.1f / (1.0f + impv);
    }
}

// ---------------------------------------------------------------------------
// XCD-aware block remap: each XCD (n&7) gets a contiguous 16-row-band slab,
// iterating cols slowest so its A slab + full B stay L2-resident.
__device__ __forceinline__ void swizzle_blk(int n, long& rowBase, long& colBase) {
    int xcd = n & 7, s = n >> 3;
    rowBase = (long)(xcd * 16 + (s & 15)) * 128;
    colBase = (long)(s >> 4) * 128;
}

// ---------------------------------------------------------------------------
// Shared GEMM core: 128x128 tile, BK=64 (16 K-iters), XOR granule swizzle.
// LDS rows are 128B (32 banks); stored granule sg holds global granule
// sg^ (row&7), applied on the GLOBAL address (global_load_lds scatters
// lane*16 so LDS-side padding/swizzle is impossible). Fragment reads then
// hit 8 distinct 4-bank groups across c16&7 -> 2-way = conflict-free.
#define GEMM_CORE(A_, B_, As_, Bs_)                                            \
    const int wave = t >> 6;                                                   \
    const int lane = t & 63;                                                   \
    const int wr = wave >> 1, wc = wave & 1;                                   \
    const int lr8 = lane >> 3;          /* row-in-8-group */                   \
    const int gr = lane & 7;            /* granule */                          \
    const int sw = ((gr ^ lr8) << 4);   /* swizzled byte offset in 128B row */ \
    const char* gA = (const char*)A_ + (rowBase + wave * 32 + lr8) * 2048 + sw;\
    const char* gB = (const char*)B_ + (colBase + wave * 32 + lr8) * 2048 + sw;\
    char* lA = (char*)As_ + wave * 4096;                                       \
    char* lB = (char*)Bs_ + wave * 4096;                                       \
    const int q = lane >> 4;                                                   \
    const int c16 = lane & 15;                                                 \
    const int xorm = c16 & 7;                                                  \
    const int oA0 = ((q ^ xorm) << 4);        /* h=0 granule offset */         \
    const int oA1 = (((4 + q) ^ xorm) << 4);  /* h=1 granule offset */         \
    const int aRow = (wr * 64 + c16) * 128;                                    \
    const int bRow = (wc * 64 + c16) * 128;                                    \
    f32x4 acc[4][4] = {};                                                      \
    for (int kt = 0; kt < 2048; kt += 128) {                                   \
        const char* a0 = gA + kt;                                              \
        const char* b0 = gB + kt;                                              \
        async16(a0, lA);                                                       \
        async16(a0 + 8 * 2048, lA + 1024);                                     \
        async16(a0 + 16 * 2048, lA + 2048);                                    \
        async16(a0 + 24 * 2048, lA + 3072);                                    \
        async16(b0, lB);                                                       \
        async16(b0 + 8 * 2048, lB + 1024);                                     \
        async16(b0 + 16 * 2048, lB + 2048);                                    \
        async16(b0 + 24 * 2048, lB + 3072);                                    \
        __syncthreads();                                                       \
        bf16x8 af[2][4], bfr[2][4];                                            \
        _Pragma("unroll")                                                      \
        for (int mi = 0; mi < 4; ++mi) {                                       \
            af[0][mi] = *(const bf16x8*)((const char*)As_ + aRow + mi * 2048 + oA0); \
            af[1][mi] = *(const bf16x8*)((const char*)As_ + aRow + mi * 2048 + oA1); \
        }                                                                      \
        _Pragma("unroll")                                                      \
        for (int ni = 0; ni < 4; ++ni) {                                       \
            bfr[0][ni] = *(const bf16x8*)((const char*)Bs_ + bRow + ni * 2048 + oA0); \
            bfr[1][ni] = *(const bf16x8*)((const char*)Bs_ + bRow + ni * 2048 + oA1); \
        }                                                                      \
        _Pragma("unroll")                                                      \
        for (int h = 0; h < 2; ++h)                                            \
            _Pragma("unroll")                                                  \
            for (int mi = 0; mi < 4; ++mi)                                     \
                _Pragma("unroll")                                              \
                for (int ni = 0; ni < 4; ++ni)                                 \
                    acc[mi][ni] = __builtin_amdgcn_mfma_f32_16x16x32_bf16(     \
                        af[h][mi], bfr[h][ni], acc[mi][ni], 0, 0, 0);          \
        __syncthreads();                                                       \
    }

// GEMM1 + fused head-mix epilogue.
// C[M=16384, N=1024] = A @ B^T (bf16, fp32 acc); columns are (k,h)-interleaved
// so each 8-col group is one k's 8 heads; epilogue applies
// out[i] = v[i] + scale_s * sum_j coef[b,i,j]*v[j] via LDS round-trip.
__global__ __launch_bounds__(256, 3) void gemm1_mix(const unsigned short* __restrict__ A,
                                                    const unsigned short* __restrict__ B,
                                                    const float* __restrict__ coef,
                                                    const int* __restrict__ causal,
                                                    unsigned short* __restrict__ C) {
    __shared__ float mixs[64 * 132];             // 33792 B, aliases As/Bs (32KB)
    __shared__ float cfs[64];
    unsigned short* As = (unsigned short*)mixs;  // 16 KB
    unsigned short* Bs = As + 8192;              // 16 KB
    const int t = threadIdx.x;
    long rowBase, colBase;
    swizzle_blk(blockIdx.x, rowBase, colBase);
    const int b = (int)(rowBase >> 12);
    if (t < 64) cfs[t] = coef[b * 64 + t];
    const int causalv = causal[0];

    GEMM_CORE(A, B, As, Bs)

    // Epilogue: two 64-row passes through LDS, mix 8 heads per k-group.
#pragma unroll
    for (int pass = 0; pass < 2; ++pass) {
        if (wr == pass) {
#pragma unroll
            for (int mi = 0; mi < 4; ++mi)
#pragma unroll
                for (int ni = 0; ni < 4; ++ni)
#pragma unroll
                    for (int r = 0; r < 4; ++r)
                        mixs[(mi * 16 + q * 4 + r) * 132 + wc * 64 + ni * 16 + c16] = acc[mi][ni][r];
        }
        __syncthreads();
        long rb2 = rowBase + pass * 64;
#pragma unroll
        for (int it = 0; it < 4; ++it) {
            int item = t + it * 256;             // 1024 = 64 rows x 16 kgroups
            int r = item >> 4, kg = item & 15;
            const float* src = mixs + r * 132 + kg * 8;
            float v[8];
#pragma unroll
            for (int j = 0; j < 8; ++j) v[j] = src[j];
            long row = rb2 + r;
            float scale = causalv ? (float)((row & 4095) + 1) * (1.0f / 4096.0f) : 1.0f;
            us8 o;
#pragma unroll
            for (int i = 0; i < 8; ++i) {
                float ts = 0.f;
#pragma unroll
                for (int j = 0; j < 8; ++j) ts += cfs[i * 8 + j] * v[j];
                o[i] = f2bf(v[i] + scale * ts);
            }
            *(us8*)(C + row * 1024 + colBase + kg * 8) = o;
        }
        __syncthreads();
    }
}

// ---------------------------------------------------------------------------
// Plain GEMM (second projection): C = A @ B^T, bf16 out.
__global__ __launch_bounds__(256, 3) void gemm_bt(const unsigned short* __restrict__ A,
                                                  const unsigned short* __restrict__ B,
                                                  unsigned short* __restrict__ C) {
    __shared__ unsigned short As[128 * 64];      // 16 KB
    __shared__ unsigned short Bs[128 * 64];      // 16 KB
    const int t = threadIdx.x;
    long rowBase, colBase;
    swizzle_blk(blockIdx.x, rowBase, colBase);

    GEMM_CORE(A, B, As, Bs)

#pragma unroll
    for (int mi = 0; mi < 4; ++mi) {
#pragma unroll
        for (int ni = 0; ni < 4; ++ni) {
            long col = colBase + wc * 64 + ni * 16 + c16;
            long row0 = rowBase + wr * 64 + mi * 16 + q * 4;
#pragma unroll
            for (int r = 0; r < 4; ++r)
                C[(row0 + r) * 1024 + col] = f2bf(acc[mi][ni][r]);
        }
    }
}

// ---------------------------------------------------------------------------
// LayerNorm over D=1024: y = ypre + out_b + x; out = (y-mu)/sqrt(var+eps)*g+b
__global__ __launch_bounds__(256) void ln_k(const unsigned short* __restrict__ ypre,
                                            const float* __restrict__ x,
                                            const float* __restrict__ outb,
                                            const float* __restrict__ gam,
                                            const float* __restrict__ bet,
                                            float* __restrict__ out) {
    int row = blockIdx.x;       // 16384
    int t = threadIdx.x;        // 256, 4 elems each
    long base = (long)row * 1024 + t * 4;
    ushort4 yp = *(const ushort4*)(ypre + base);
    float4 xv = *(const float4*)(x + base);
    float4 bv = *(const float4*)(outb + t * 4);
    float y0 = bf2f(yp.x) + xv.x + bv.x;
    float y1 = bf2f(yp.y) + xv.y + bv.y;
    float y2 = bf2f(yp.z) + xv.z + bv.z;
    float y3 = bf2f(yp.w) + xv.w + bv.w;
    float s = y0 + y1 + y2 + y3;
    float ss = y0 * y0 + y1 * y1 + y2 * y2 + y3 * y3;
    for (int off = 32; off; off >>= 1) {
        s += __shfl_down(s, off);
        ss += __shfl_down(ss, off);
    }
    __shared__ float red[8];
    int wv = t >> 6, ln = t & 63;
    if (ln == 0) { red[wv] = s; red[4 + wv] = ss; }
    __syncthreads();
    if (t == 0) {
        float S1 = red[0] + red[1] + red[2] + red[3];
        float S2 = red[4] + red[5] + red[6] + red[7];
        float mu = S1 * (1.0f / 1024.0f);
        float var = S2 * (1.0f / 1024.0f) - mu * mu;
        red[0] = mu;
        red[1] = 1.0f / sqrtf(var + 1e-5f);
    }
    __syncthreads();
    float mu = red[0], rs = red[1];
    float4 gv = *(const float4*)(gam + t * 4);
    float4 bb = *(const float4*)(bet + t * 4);
    float4 o;
    o.x = (y0 - mu) * rs * gv.x + bb.x;
    o.y = (y1 - mu) * rs * gv.y + bb.y;
    o.z = (y2 - mu) * rs * gv.z + bb.z;
    o.w = (y3 - mu) * rs * gv.w + bb.w;
    *(float4*)(out + base) = o;
}

// ---------------------------------------------------------------------------
extern "C" void kernel_launch(void* const* d_in, const int* in_sizes, int n_in,
                              void* d_out, int out_size, void* d_ws, size_t ws_size,
                              hipStream_t stream) {
    const float* x       = (const float*)d_in[0];
    const float* W_proj  = (const float*)d_in[1];
    const float* freqs   = (const float*)d_in[2];
    const float* pol_W   = (const float*)d_in[3];
    const float* pol_b   = (const float*)d_in[4];
    const float* imp_W1  = (const float*)d_in[5];
    const float* imp_b1  = (const float*)d_in[6];
    const float* imp_W2  = (const float*)d_in[7];
    const float* imp_b2  = (const float*)d_in[8];
    const float* out_W   = (const float*)d_in[9];
    const float* out_b   = (const float*)d_in[10];
    const float* ln_g    = (const float*)d_in[11];
    const float* ln_b    = (const float*)d_in[12];
    const int*   causal  = (const int*)d_in[13];
    float* out = (float*)d_out;

    char* ws = (char*)d_ws;
    unsigned short* xb      = (unsigned short*)(ws + 0);          // 32MB, dead after gemm1 -> reused as ypre
    unsigned short* merged  = (unsigned short*)(ws + 33554432);   // 32MB
    unsigned short* w1b     = (unsigned short*)(ws + 67108864);   // 2MB
    unsigned short* wob     = (unsigned short*)(ws + 69206016);   // 2MB
    float* xbar             = (float*)(ws + 71303168);            // 16KB
    float* summary          = (float*)(ws + 71319552);            // 16KB
    float* coef             = (float*)(ws + 71335936);            // 1KB
    unsigned short* ypre    = xb;

    hipMemsetAsync(xbar, 0, 4096 * sizeof(float), stream);
    prep_k<<<8192, 256, 0, stream>>>(W_proj, freqs, out_W, w1b, wob);
    xbar_cast<<<2048, 256, 0, stream>>>(x, xb, xbar);
    summary_k<<<1024, 256, 0, stream>>>(xbar, W_proj, freqs, summary);
    imp_k<<<1, 256, 0, stream>>>(summary, pol_W, pol_b, imp_W1, imp_b1,
                                 imp_W2, imp_b2, coef, out + 16777216);
    gemm1_mix<<<1024, 256, 0, stream>>>(xb, w1b, coef, causal, merged);
    gemm_bt<<<1024, 256, 0, stream>>>(merged, wob, ypre);
    ln_k<<<16384, 256, 0, stream>>>(ypre, x, out_b, ln_g, ln_b, out);
}

// Round 4
// 319.307 us; speedup vs baseline: 1.4675x; 1.2628x over previous
//
#include <hip/hip_runtime.h>

typedef __bf16 bf16x8 __attribute__((ext_vector_type(8)));
typedef float f32x4 __attribute__((ext_vector_type(4)));
typedef unsigned short us8 __attribute__((ext_vector_type(8)));

#define PI_F 3.14159265358979323846f

__device__ __forceinline__ unsigned short f2bf(float f) {
    unsigned u = __float_as_uint(f);
    u += 0x7FFFu + ((u >> 16) & 1u);   // RNE
    return (unsigned short)(u >> 16);
}
__device__ __forceinline__ float bf2f(unsigned short h) {
    return __uint_as_float(((unsigned)h) << 16);
}

__device__ __forceinline__ void async16(const void* g, void* l) {
    __builtin_amdgcn_global_load_lds(
        (const __attribute__((address_space(1))) unsigned int*)g,
        (__attribute__((address_space(3))) unsigned int*)l, 16, 0, 0);
}

// ---------------------------------------------------------------------------
// Merged weight prep.
// idx < 1M : W1b[(k*8+h)*1024 + d] = bf16( W_proj[h,k,d] * cos(pi*freq[h,k]) )
// else     : Wob[n*1024 + (k*8+h)] = bf16( out_W[n, h*128+k] )
__global__ __launch_bounds__(256) void prep_k(const float* __restrict__ W,
                                              const float* __restrict__ fr,
                                              const float* __restrict__ Wo,
                                              unsigned short* __restrict__ W1b,
                                              unsigned short* __restrict__ Wob) {
    int idx = blockIdx.x * 256 + threadIdx.x;      // 2M
    if (idx < (1 << 20)) {
        int n = idx >> 10, d = idx & 1023;
        int k = n >> 3, h = n & 7;
        float c = cosf(fr[h * 128 + k] * PI_F);
        W1b[idx] = f2bf(W[((h * 128 + k) << 10) + d] * c);
    } else {
        int i2 = idx - (1 << 20);
        int n = i2 >> 10, dp = i2 & 1023;
        int k = dp >> 3, h = dp & 7;
        Wob[i2] = f2bf(Wo[(n << 10) + h * 128 + k]);
    }
}

// ---------------------------------------------------------------------------
// x -> bf16 cast + per-(b,d) partial column sums written as PLAIN stores
// (round-3's contiguous per-lane atomicAdd serialized at L2: 121us, 831GB/s).
// part[bid][1024] fp32, reduced by xbar_r.
__global__ __launch_bounds__(256) void xbar_cast(const float* __restrict__ x,
                                                 unsigned short* __restrict__ xb,
                                                 float* __restrict__ part) {
    int bid = blockIdx.x;            // 1024
    int b = bid >> 8;
    int s0 = (bid & 255) * 16;
    int t = threadIdx.x;             // d4 index
    float a0 = 0.f, a1 = 0.f, a2 = 0.f, a3 = 0.f;
    for (int i = 0; i < 16; ++i) {
        long row = (long)b * 4096 + s0 + i;
        float4 v = ((const float4*)x)[row * 256 + t];
        a0 += v.x; a1 += v.y; a2 += v.z; a3 += v.w;
        ushort4 u;
        u.x = f2bf(v.x); u.y = f2bf(v.y); u.z = f2bf(v.z); u.w = f2bf(v.w);
        ((ushort4*)xb)[row * 256 + t] = u;
    }
    float4 p; p.x = a0; p.y = a1; p.z = a2; p.w = a3;
    ((float4*)part)[bid * 256 + t] = p;
}

// Reduce part[1024][1024] -> xbar[4][1024]. 32 blocks, fully coalesced.
__global__ __launch_bounds__(256) void xbar_r(const float* __restrict__ part,
                                              float* __restrict__ xbar) {
    __shared__ float sl[256];
    int blk = blockIdx.x;            // 32 = b*8 + dgrp
    int b = blk >> 3, dgrp = blk & 7;
    int t = threadIdx.x;
    int col = dgrp * 128 + (t & 127);
    int ih = t >> 7;                 // split the 256 cast-blocks of this b in half
    float s = 0.f;
    for (int i = 0; i < 128; ++i) {
        int cb = b * 256 + ih * 128 + i;
        s += part[cb * 1024 + col];
    }
    sl[t] = s;
    __syncthreads();
    if (t < 128) xbar[b * 1024 + col] = sl[t] + sl[t + 128];
}

// ---------------------------------------------------------------------------
// summary[b,h,k] = (1/S) * dot(xbar[b,:], W_proj[h,k,:]) * cos(pi*freq[h,k])
// one wave per output.
__global__ __launch_bounds__(256) void summary_k(const float* __restrict__ xbar,
                                                 const float* __restrict__ W,
                                                 const float* __restrict__ fr,
                                                 float* __restrict__ summary) {
    int wave = (blockIdx.x * 256 + threadIdx.x) >> 6;   // 0..4095 = b*1024+h*128+k
    int lane = threadIdx.x & 63;
    int b = wave >> 10, hk = wave & 1023;
    int h = hk >> 7, k = hk & 127;
    const float* wrow = &W[(h * 128 + k) << 10];
    const float* xrow = &xbar[b << 10];
    float s = 0.f;
    for (int d = lane; d < 1024; d += 64) s += xrow[d] * wrow[d];
    for (int off = 32; off; off >>= 1) s += __shfl_down(s, off);
    if (lane == 0) {
        float c = cosf(fr[h * 128 + k] * PI_F);
        summary[wave] = s * c * (1.0f / 4096.0f);
    }
}

// ---------------------------------------------------------------------------
// pol -> normalize -> dots -> gelu MLP -> softplus -> impedance & coef. 1 block.
__global__ __launch_bounds__(256) void imp_k(const float* __restrict__ summary,
                                             const float* __restrict__ pol_W,
                                             const float* __restrict__ pol_b,
                                             const float* __restrict__ imp_W1,
                                             const float* __restrict__ imp_b1,
                                             const float* __restrict__ imp_W2,
                                             const float* __restrict__ imp_b2,
                                             float* __restrict__ coef_out,
                                             float* __restrict__ imp_out) {
    __shared__ float pol[4][8][32];
    __shared__ float rn[32];
    int t = threadIdx.x;
    for (int o = t; o < 1024; o += 256) {
        int b = o >> 8, h = (o >> 5) & 7, p = o & 31;
        const float* srow = &summary[(b * 8 + h) * 128];
        const float* wrow = &pol_W[(h * 32 + p) * 128];
        float acc = pol_b[h * 32 + p];
        for (int k = 0; k < 128; ++k) acc += srow[k] * wrow[k];
        pol[b][h][p] = tanhf(acc);
    }
    __syncthreads();
    if (t < 32) {
        int b = t >> 3, h = t & 7;
        float ss = 0.f;
        for (int p = 0; p < 32; ++p) { float v = pol[b][h][p]; ss += v * v; }
        rn[t] = 1.0f / fmaxf(sqrtf(ss), 1e-12f);
    }
    __syncthreads();
    {
        int b = t >> 6, i = (t >> 3) & 7, j = t & 7;
        float d = 0.f;
        for (int p = 0; p < 32; ++p) d += pol[b][i][p] * pol[b][j][p];
        d *= rn[b * 8 + i] * rn[b * 8 + j];
        float s = imp_b2[0];
        for (int c = 0; c < 16; ++c) {
            float z = d * imp_W1[c] + imp_b1[c];
            float gl = 0.5f * z * (1.0f + erff(z * 0.70710678118654752f));
            s += gl * imp_W2[c];
        }
        float sp = fmaxf(s, 0.0f) + log1pf(expf(-fabsf(s)));   // softplus
        float impv = (i == j) ? 0.0f : sp;
        imp_out[t] = impv;
        coef_out[t] = (i == j) ? 0.0f : 0.1f / (1.0f + impv);
    }
}

// ---------------------------------------------------------------------------
// XCD-aware block remap: each XCD (n&7) gets a contiguous 16-row-band slab,
// iterating cols slowest so its A slab + full B stay L2-resident.
__device__ __forceinline__ void swizzle_blk(int n, long& rowBase, long& colBase) {
    int xcd = n & 7, s = n >> 3;
    rowBase = (long)(xcd * 16 + (s & 15)) * 128;
    colBase = (long)(s >> 4) * 128;
}

// ---------------------------------------------------------------------------
// Shared GEMM core: 128x128 tile, BK=64 (16 K-iters), XOR granule swizzle.
// LDS rows are 128B (32 banks); stored granule sg holds global granule
// sg^ (row&7), applied on the GLOBAL address (global_load_lds scatters
// lane*16 so LDS-side padding/swizzle is impossible). Fragment reads then
// hit 8 distinct 4-bank groups across c16&7 -> 2-way = conflict-free.
#define GEMM_CORE(A_, B_, As_, Bs_)                                            \
    const int wave = t >> 6;                                                   \
    const int lane = t & 63;                                                   \
    const int wr = wave >> 1, wc = wave & 1;                                   \
    const int lr8 = lane >> 3;          /* row-in-8-group */                   \
    const int gr = lane & 7;            /* granule */                          \
    const int sw = ((gr ^ lr8) << 4);   /* swizzled byte offset in 128B row */ \
    const char* gA = (const char*)A_ + (rowBase + wave * 32 + lr8) * 2048 + sw;\
    const char* gB = (const char*)B_ + (colBase + wave * 32 + lr8) * 2048 + sw;\
    char* lA = (char*)As_ + wave * 4096;                                       \
    char* lB = (char*)Bs_ + wave * 4096;                                       \
    const int q = lane >> 4;                                                   \
    const int c16 = lane & 15;                                                 \
    const int xorm = c16 & 7;                                                  \
    const int oA0 = ((q ^ xorm) << 4);        /* h=0 granule offset */         \
    const int oA1 = (((4 + q) ^ xorm) << 4);  /* h=1 granule offset */         \
    const int aRow = (wr * 64 + c16) * 128;                                    \
    const int bRow = (wc * 64 + c16) * 128;                                    \
    f32x4 acc[4][4] = {};                                                      \
    for (int kt = 0; kt < 2048; kt += 128) {                                   \
        const char* a0 = gA + kt;                                              \
        const char* b0 = gB + kt;                                              \
        async16(a0, lA);                                                       \
        async16(a0 + 8 * 2048, lA + 1024);                                     \
        async16(a0 + 16 * 2048, lA + 2048);                                    \
        async16(a0 + 24 * 2048, lA + 3072);                                    \
        async16(b0, lB);                                                       \
        async16(b0 + 8 * 2048, lB + 1024);                                     \
        async16(b0 + 16 * 2048, lB + 2048);                                    \
        async16(b0 + 24 * 2048, lB + 3072);                                    \
        __syncthreads();                                                       \
        bf16x8 af[2][4], bfr[2][4];                                            \
        _Pragma("unroll")                                                      \
        for (int mi = 0; mi < 4; ++mi) {                                       \
            af[0][mi] = *(const bf16x8*)((const char*)As_ + aRow + mi * 2048 + oA0); \
            af[1][mi] = *(const bf16x8*)((const char*)As_ + aRow + mi * 2048 + oA1); \
        }                                                                      \
        _Pragma("unroll")                                                      \
        for (int ni = 0; ni < 4; ++ni) {                                       \
            bfr[0][ni] = *(const bf16x8*)((const char*)Bs_ + bRow + ni * 2048 + oA0); \
            bfr[1][ni] = *(const bf16x8*)((const char*)Bs_ + bRow + ni * 2048 + oA1); \
        }                                                                      \
        _Pragma("unroll")                                                      \
        for (int h = 0; h < 2; ++h)                                            \
            _Pragma("unroll")                                                  \
            for (int mi = 0; mi < 4; ++mi)                                     \
                _Pragma("unroll")                                              \
                for (int ni = 0; ni < 4; ++ni)                                 \
                    acc[mi][ni] = __builtin_amdgcn_mfma_f32_16x16x32_bf16(     \
                        af[h][mi], bfr[h][ni], acc[mi][ni], 0, 0, 0);          \
        __syncthreads();                                                       \
    }

// GEMM1 + fused head-mix epilogue.
// C[M=16384, N=1024] = A @ B^T (bf16, fp32 acc); columns are (k,h)-interleaved
// so each 8-col group is one k's 8 heads; epilogue applies
// out[i] = v[i] + scale_s * sum_j coef[b,i,j]*v[j] via LDS round-trip.
__global__ __launch_bounds__(256, 3) void gemm1_mix(const unsigned short* __restrict__ A,
                                                    const unsigned short* __restrict__ B,
                                                    const float* __restrict__ coef,
                                                    const int* __restrict__ causal,
                                                    unsigned short* __restrict__ C) {
    __shared__ float mixs[64 * 132];             // 33792 B, aliases As/Bs (32KB)
    __shared__ float cfs[64];
    unsigned short* As = (unsigned short*)mixs;  // 16 KB
    unsigned short* Bs = As + 8192;              // 16 KB
    const int t = threadIdx.x;
    long rowBase, colBase;
    swizzle_blk(blockIdx.x, rowBase, colBase);
    const int b = (int)(rowBase >> 12);
    if (t < 64) cfs[t] = coef[b * 64 + t];
    const int causalv = causal[0];

    GEMM_CORE(A, B, As, Bs)

    // Epilogue: two 64-row passes through LDS, mix 8 heads per k-group.
#pragma unroll
    for (int pass = 0; pass < 2; ++pass) {
        if (wr == pass) {
#pragma unroll
            for (int mi = 0; mi < 4; ++mi)
#pragma unroll
                for (int ni = 0; ni < 4; ++ni)
#pragma unroll
                    for (int r = 0; r < 4; ++r)
                        mixs[(mi * 16 + q * 4 + r) * 132 + wc * 64 + ni * 16 + c16] = acc[mi][ni][r];
        }
        __syncthreads();
        long rb2 = rowBase + pass * 64;
#pragma unroll
        for (int it = 0; it < 4; ++it) {
            int item = t + it * 256;             // 1024 = 64 rows x 16 kgroups
            int r = item >> 4, kg = item & 15;
            const float* src = mixs + r * 132 + kg * 8;
            float v[8];
#pragma unroll
            for (int j = 0; j < 8; ++j) v[j] = src[j];
            long row = rb2 + r;
            float scale = causalv ? (float)((row & 4095) + 1) * (1.0f / 4096.0f) : 1.0f;
            us8 o;
#pragma unroll
            for (int i = 0; i < 8; ++i) {
                float ts = 0.f;
#pragma unroll
                for (int j = 0; j < 8; ++j) ts += cfs[i * 8 + j] * v[j];
                o[i] = f2bf(v[i] + scale * ts);
            }
            *(us8*)(C + row * 1024 + colBase + kg * 8) = o;
        }
        __syncthreads();
    }
}

// ---------------------------------------------------------------------------
// Plain GEMM (second projection): C = A @ B^T, bf16 out.
__global__ __launch_bounds__(256, 3) void gemm_bt(const unsigned short* __restrict__ A,
                                                  const unsigned short* __restrict__ B,
                                                  unsigned short* __restrict__ C) {
    __shared__ unsigned short As[128 * 64];      // 16 KB
    __shared__ unsigned short Bs[128 * 64];      // 16 KB
    const int t = threadIdx.x;
    long rowBase, colBase;
    swizzle_blk(blockIdx.x, rowBase, colBase);

    GEMM_CORE(A, B, As, Bs)

#pragma unroll
    for (int mi = 0; mi < 4; ++mi) {
#pragma unroll
        for (int ni = 0; ni < 4; ++ni) {
            long col = colBase + wc * 64 + ni * 16 + c16;
            long row0 = rowBase + wr * 64 + mi * 16 + q * 4;
#pragma unroll
            for (int r = 0; r < 4; ++r)
                C[(row0 + r) * 1024 + col] = f2bf(acc[mi][ni][r]);
        }
    }
}

// ---------------------------------------------------------------------------
// LayerNorm over D=1024: y = ypre + out_b + x; out = (y-mu)/sqrt(var+eps)*g+b
__global__ __launch_bounds__(256) void ln_k(const unsigned short* __restrict__ ypre,
                                            const float* __restrict__ x,
                                            const float* __restrict__ outb,
                                            const float* __restrict__ gam,
                                            const float* __restrict__ bet,
                                            float* __restrict__ out) {
    int row = blockIdx.x;       // 16384
    int t = threadIdx.x;        // 256, 4 elems each
    long base = (long)row * 1024 + t * 4;
    ushort4 yp = *(const ushort4*)(ypre + base);
    float4 xv = *(const float4*)(x + base);
    float4 bv = *(const float4*)(outb + t * 4);
    float y0 = bf2f(yp.x) + xv.x + bv.x;
    float y1 = bf2f(yp.y) + xv.y + bv.y;
    float y2 = bf2f(yp.z) + xv.z + bv.z;
    float y3 = bf2f(yp.w) + xv.w + bv.w;
    float s = y0 + y1 + y2 + y3;
    float ss = y0 * y0 + y1 * y1 + y2 * y2 + y3 * y3;
    for (int off = 32; off; off >>= 1) {
        s += __shfl_down(s, off);
        ss += __shfl_down(ss, off);
    }
    __shared__ float red[8];
    int wv = t >> 6, ln = t & 63;
    if (ln == 0) { red[wv] = s; red[4 + wv] = ss; }
    __syncthreads();
    if (t == 0) {
        float S1 = red[0] + red[1] + red[2] + red[3];
        float S2 = red[4] + red[5] + red[6] + red[7];
        float mu = S1 * (1.0f / 1024.0f);
        float var = S2 * (1.0f / 1024.0f) - mu * mu;
        red[0] = mu;
        red[1] = 1.0f / sqrtf(var + 1e-5f);
    }
    __syncthreads();
    float mu = red[0], rs = red[1];
    float4 gv = *(const float4*)(gam + t * 4);
    float4 bb = *(const float4*)(bet + t * 4);
    float4 o;
    o.x = (y0 - mu) * rs * gv.x + bb.x;
    o.y = (y1 - mu) * rs * gv.y + bb.y;
    o.z = (y2 - mu) * rs * gv.z + bb.z;
    o.w = (y3 - mu) * rs * gv.w + bb.w;
    *(float4*)(out + base) = o;
}

// ---------------------------------------------------------------------------
extern "C" void kernel_launch(void* const* d_in, const int* in_sizes, int n_in,
                              void* d_out, int out_size, void* d_ws, size_t ws_size,
                              hipStream_t stream) {
    const float* x       = (const float*)d_in[0];
    const float* W_proj  = (const float*)d_in[1];
    const float* freqs   = (const float*)d_in[2];
    const float* pol_W   = (const float*)d_in[3];
    const float* pol_b   = (const float*)d_in[4];
    const float* imp_W1  = (const float*)d_in[5];
    const float* imp_b1  = (const float*)d_in[6];
    const float* imp_W2  = (const float*)d_in[7];
    const float* imp_b2  = (const float*)d_in[8];
    const float* out_W   = (const float*)d_in[9];
    const float* out_b   = (const float*)d_in[10];
    const float* ln_g    = (const float*)d_in[11];
    const float* ln_b    = (const float*)d_in[12];
    const int*   causal  = (const int*)d_in[13];
    float* out = (float*)d_out;

    char* ws = (char*)d_ws;
    unsigned short* xb      = (unsigned short*)(ws + 0);          // 32MB, dead after gemm1 -> reused as ypre
    unsigned short* merged  = (unsigned short*)(ws + 33554432);   // 32MB
    unsigned short* w1b     = (unsigned short*)(ws + 67108864);   // 2MB
    unsigned short* wob     = (unsigned short*)(ws + 69206016);   // 2MB
    float* xbar             = (float*)(ws + 71303168);            // 16KB
    float* summary          = (float*)(ws + 71319552);            // 16KB
    float* coef             = (float*)(ws + 71335936);            // 1KB
    float* part             = (float*)merged;                     // 4MB, dead before gemm1_mix writes merged
    unsigned short* ypre    = xb;

    prep_k<<<8192, 256, 0, stream>>>(W_proj, freqs, out_W, w1b, wob);
    xbar_cast<<<1024, 256, 0, stream>>>(x, xb, part);
    xbar_r<<<32, 256, 0, stream>>>(part, xbar);
    summary_k<<<1024, 256, 0, stream>>>(xbar, W_proj, freqs, summary);
    imp_k<<<1, 256, 0, stream>>>(summary, pol_W, pol_b, imp_W1, imp_b1,
                                 imp_W2, imp_b2, coef, out + 16777216);
    gemm1_mix<<<1024, 256, 0, stream>>>(xb, w1b, coef, causal, merged);
    gemm_bt<<<1024, 256, 0, stream>>>(merged, wob, ypre);
    ln_k<<<16384, 256, 0, stream>>>(ypre, x, out_b, ln_g, ln_b, out);
}

// Round 5
// 300.550 us; speedup vs baseline: 1.5591x; 1.0624x over previous
//
#include <hip/hip_runtime.h>

typedef __bf16 bf16x8 __attribute__((ext_vector_type(8)));
typedef float f32x4 __attribute__((ext_vector_type(4)));
typedef unsigned short us8 __attribute__((ext_vector_type(8)));

#define PI_F 3.14159265358979323846f

__device__ __forceinline__ unsigned short f2bf(float f) {
    unsigned u = __float_as_uint(f);
    u += 0x7FFFu + ((u >> 16) & 1u);   // RNE
    return (unsigned short)(u >> 16);
}
__device__ __forceinline__ float bf2f(unsigned short h) {
    return __uint_as_float(((unsigned)h) << 16);
}

__device__ __forceinline__ void async16(const void* g, void* l) {
    __builtin_amdgcn_global_load_lds(
        (const __attribute__((address_space(1))) unsigned int*)g,
        (__attribute__((address_space(3))) unsigned int*)l, 16, 0, 0);
}

// ---------------------------------------------------------------------------
// Merged weight prep.
// idx < 1M : W1b[(k*8+h)*1024 + d] = bf16( W_proj[h,k,d] * cos(pi*freq[h,k]) )
// else     : Wob[n*1024 + (k*8+h)] = bf16( out_W[n, h*128+k] )
__global__ __launch_bounds__(256) void prep_k(const float* __restrict__ W,
                                              const float* __restrict__ fr,
                                              const float* __restrict__ Wo,
                                              unsigned short* __restrict__ W1b,
                                              unsigned short* __restrict__ Wob) {
    int idx = blockIdx.x * 256 + threadIdx.x;      // 2M
    if (idx < (1 << 20)) {
        int n = idx >> 10, d = idx & 1023;
        int k = n >> 3, h = n & 7;
        float c = cosf(fr[h * 128 + k] * PI_F);
        W1b[idx] = f2bf(W[((h * 128 + k) << 10) + d] * c);
    } else {
        int i2 = idx - (1 << 20);
        int n = i2 >> 10, dp = i2 & 1023;
        int k = dp >> 3, h = dp & 7;
        Wob[i2] = f2bf(Wo[(n << 10) + h * 128 + k]);
    }
}

// ---------------------------------------------------------------------------
// x -> bf16 cast + per-(b,d) partial column sums via PLAIN stores
// (contiguous per-lane atomicAdd serialized at L2: 121us in round 3).
__global__ __launch_bounds__(256) void xbar_cast(const float* __restrict__ x,
                                                 unsigned short* __restrict__ xb,
                                                 float* __restrict__ part) {
    int bid = blockIdx.x;            // 1024
    int b = bid >> 8;
    int s0 = (bid & 255) * 16;
    int t = threadIdx.x;             // d4 index
    float a0 = 0.f, a1 = 0.f, a2 = 0.f, a3 = 0.f;
    for (int i = 0; i < 16; ++i) {
        long row = (long)b * 4096 + s0 + i;
        float4 v = ((const float4*)x)[row * 256 + t];
        a0 += v.x; a1 += v.y; a2 += v.z; a3 += v.w;
        ushort4 u;
        u.x = f2bf(v.x); u.y = f2bf(v.y); u.z = f2bf(v.z); u.w = f2bf(v.w);
        ((ushort4*)xb)[row * 256 + t] = u;
    }
    float4 p; p.x = a0; p.y = a1; p.z = a2; p.w = a3;
    ((float4*)part)[bid * 256 + t] = p;
}

// Reduce part[1024][1024] -> xbar[4][1024]. 32 blocks, fully coalesced.
__global__ __launch_bounds__(256) void xbar_r(const float* __restrict__ part,
                                              float* __restrict__ xbar) {
    __shared__ float sl[256];
    int blk = blockIdx.x;            // 32 = b*8 + dgrp
    int b = blk >> 3, dgrp = blk & 7;
    int t = threadIdx.x;
    int col = dgrp * 128 + (t & 127);
    int ih = t >> 7;
    float s = 0.f;
    for (int i = 0; i < 128; ++i) {
        int cb = b * 256 + ih * 128 + i;
        s += part[cb * 1024 + col];
    }
    sl[t] = s;
    __syncthreads();
    if (t < 128) xbar[b * 1024 + col] = sl[t] + sl[t + 128];
}

// ---------------------------------------------------------------------------
// summary[b,h,k] = (1/S) * dot(xbar[b,:], W_proj[h,k,:]) * cos(pi*freq[h,k])
__global__ __launch_bounds__(256) void summary_k(const float* __restrict__ xbar,
                                                 const float* __restrict__ W,
                                                 const float* __restrict__ fr,
                                                 float* __restrict__ summary) {
    int wave = (blockIdx.x * 256 + threadIdx.x) >> 6;   // 0..4095 = b*1024+h*128+k
    int lane = threadIdx.x & 63;
    int b = wave >> 10, hk = wave & 1023;
    int h = hk >> 7, k = hk & 127;
    const float* wrow = &W[(h * 128 + k) << 10];
    const float* xrow = &xbar[b << 10];
    float s = 0.f;
    for (int d = lane; d < 1024; d += 64) s += xrow[d] * wrow[d];
    for (int off = 32; off; off >>= 1) s += __shfl_down(s, off);
    if (lane == 0) {
        float c = cosf(fr[h * 128 + k] * PI_F);
        summary[wave] = s * c * (1.0f / 4096.0f);
    }
}

// ---------------------------------------------------------------------------
// pol -> normalize -> dots -> gelu MLP -> softplus -> impedance & coef. 1 block.
__global__ __launch_bounds__(256) void imp_k(const float* __restrict__ summary,
                                             const float* __restrict__ pol_W,
                                             const float* __restrict__ pol_b,
                                             const float* __restrict__ imp_W1,
                                             const float* __restrict__ imp_b1,
                                             const float* __restrict__ imp_W2,
                                             const float* __restrict__ imp_b2,
                                             float* __restrict__ coef_out,
                                             float* __restrict__ imp_out) {
    __shared__ float pol[4][8][32];
    __shared__ float rn[32];
    int t = threadIdx.x;
    for (int o = t; o < 1024; o += 256) {
        int b = o >> 8, h = (o >> 5) & 7, p = o & 31;
        const float* srow = &summary[(b * 8 + h) * 128];
        const float* wrow = &pol_W[(h * 32 + p) * 128];
        float acc = pol_b[h * 32 + p];
        for (int k = 0; k < 128; ++k) acc += srow[k] * wrow[k];
        pol[b][h][p] = tanhf(acc);
    }
    __syncthreads();
    if (t < 32) {
        int b = t >> 3, h = t & 7;
        float ss = 0.f;
        for (int p = 0; p < 32; ++p) { float v = pol[b][h][p]; ss += v * v; }
        rn[t] = 1.0f / fmaxf(sqrtf(ss), 1e-12f);
    }
    __syncthreads();
    {
        int b = t >> 6, i = (t >> 3) & 7, j = t & 7;
        float d = 0.f;
        for (int p = 0; p < 32; ++p) d += pol[b][i][p] * pol[b][j][p];
        d *= rn[b * 8 + i] * rn[b * 8 + j];
        float s = imp_b2[0];
        for (int c = 0; c < 16; ++c) {
            float z = d * imp_W1[c] + imp_b1[c];
            float gl = 0.5f * z * (1.0f + erff(z * 0.70710678118654752f));
            s += gl * imp_W2[c];
        }
        float sp = fmaxf(s, 0.0f) + log1pf(expf(-fabsf(s)));   // softplus
        float impv = (i == j) ? 0.0f : sp;
        imp_out[t] = impv;
        coef_out[t] = (i == j) ? 0.0f : 0.1f / (1.0f + impv);
    }
}

// ---------------------------------------------------------------------------
// XCD-aware block remap (verified: FETCH 132->62 MB): each XCD (n&7) gets a
// contiguous 16-row-band slab; cols iterate slowest.
__device__ __forceinline__ void swizzle_blk(int n, long& rowBase, long& colBase) {
    int xcd = n & 7, s = n >> 3;
    rowBase = (long)(xcd * 16 + (s & 15)) * 128;
    colBase = (long)(s >> 4) * 128;
}

// ---------------------------------------------------------------------------
// Round-1 proven GEMM core: 128x128 tile, BK=32, global_load_lds x16B,
// 4 waves x (4x4) 16x16x32 MFMA. (BK=64 rewrite regressed: occupancy 33->20%,
// MfmaUtil 26->18% — reverted. Bank conflicts ~4M are tolerated, m136.)
#define GEMM_CORE(A_, B_, As_, Bs_)                                            \
    const int wave = t >> 6;                                                   \
    const int lane = t & 63;                                                   \
    const int wr = wave >> 1, wc = wave & 1;                                   \
    const int lr = lane >> 2;                                                  \
    const int lb = (lane & 3) * 16;                                            \
    const char* gA = (const char*)A_ + (rowBase + wave * 32 + lr) * 2048 + lb; \
    const char* gB = (const char*)B_ + (colBase + wave * 32 + lr) * 2048 + lb; \
    char* lA = (char*)As_ + wave * 2048;                                       \
    char* lB = (char*)Bs_ + wave * 2048;                                       \
    const int q = lane >> 4;                                                   \
    const int c16 = lane & 15;                                                 \
    f32x4 acc[4][4] = {};                                                      \
    for (int kt = 0; kt < 1024; kt += 32) {                                    \
        const char* a0 = gA + kt * 2;                                          \
        const char* b0 = gB + kt * 2;                                          \
        async16(a0, lA);                                                       \
        async16(a0 + 16 * 2048, lA + 1024);                                    \
        async16(b0, lB);                                                       \
        async16(b0 + 16 * 2048, lB + 1024);                                    \
        __syncthreads();                                                       \
        bf16x8 af[4], bfr[4];                                                  \
        _Pragma("unroll")                                                      \
        for (int mi = 0; mi < 4; ++mi)                                         \
            af[mi] = *(const bf16x8*)((const char*)As_ +                       \
                       ((wr * 64 + mi * 16 + c16) * 32 + q * 8) * 2);          \
        _Pragma("unroll")                                                      \
        for (int ni = 0; ni < 4; ++ni)                                         \
            bfr[ni] = *(const bf16x8*)((const char*)Bs_ +                      \
                       ((wc * 64 + ni * 16 + c16) * 32 + q * 8) * 2);          \
        _Pragma("unroll")                                                      \
        for (int mi = 0; mi < 4; ++mi)                                         \
            _Pragma("unroll")                                                  \
            for (int ni = 0; ni < 4; ++ni)                                     \
                acc[mi][ni] = __builtin_amdgcn_mfma_f32_16x16x32_bf16(         \
                    af[mi], bfr[ni], acc[mi][ni], 0, 0, 0);                    \
        __syncthreads();                                                       \
    }

// GEMM1 + fused head-mix epilogue. Columns (k,h)-interleaved; epilogue does
// out[i] = v[i] + scale_s * sum_j coef[b,i,j]*v[j] via a SLIM 16-row LDS
// scratch (8.45 KB, aliased inside the 16 KB As/Bs region -> no LDS growth).
__global__ __launch_bounds__(256, 3) void gemm1_mix(const unsigned short* __restrict__ A,
                                                    const unsigned short* __restrict__ B,
                                                    const float* __restrict__ coef,
                                                    const int* __restrict__ causal,
                                                    unsigned short* __restrict__ C) {
    __shared__ char smem[16384];
    __shared__ float cfs[64];
    unsigned short* As = (unsigned short*)smem;          // 8 KB
    unsigned short* Bs = (unsigned short*)(smem + 8192); // 8 KB
    float* mixt = (float*)smem;                          // 16x132 fp32 = 8448 B
    const int t = threadIdx.x;
    long rowBase, colBase;
    swizzle_blk(blockIdx.x, rowBase, colBase);
    const int b = (int)(rowBase >> 12);
    if (t < 64) cfs[t] = coef[b * 64 + t];
    const int causalv = causal[0];

    GEMM_CORE(A, B, As, Bs)

    // 8 passes x 16 rows: waves with wr==p>>2 dump acc[p&3] to LDS, all
    // 256 threads mix one (row, kgroup) item each and store us8.
    const int r16 = t >> 4, kg = t & 15;
#pragma unroll
    for (int p = 0; p < 8; ++p) {
        if (wr == (p >> 2)) {
            int mi = p & 3;
#pragma unroll
            for (int ni = 0; ni < 4; ++ni)
#pragma unroll
                for (int r = 0; r < 4; ++r)
                    mixt[(q * 4 + r) * 132 + wc * 64 + ni * 16 + c16] = acc[mi][ni][r];
        }
        __syncthreads();
        const float* src = mixt + r16 * 132 + kg * 8;
        float v[8];
#pragma unroll
        for (int j = 0; j < 8; ++j) v[j] = src[j];
        long row = rowBase + p * 16 + r16;
        float scale = causalv ? (float)((row & 4095) + 1) * (1.0f / 4096.0f) : 1.0f;
        us8 o;
#pragma unroll
        for (int i = 0; i < 8; ++i) {
            float ts = 0.f;
#pragma unroll
            for (int j = 0; j < 8; ++j) ts += cfs[i * 8 + j] * v[j];
            o[i] = f2bf(v[i] + scale * ts);
        }
        *(us8*)(C + row * 1024 + colBase + kg * 8) = o;
        __syncthreads();
    }
}

// ---------------------------------------------------------------------------
// Plain GEMM (second projection): C = A @ B^T, bf16 out. Round-1 epilogue.
__global__ __launch_bounds__(256, 3) void gemm_bt(const unsigned short* __restrict__ A,
                                                  const unsigned short* __restrict__ B,
                                                  unsigned short* __restrict__ C) {
    __shared__ unsigned short As[128 * 32];
    __shared__ unsigned short Bs[128 * 32];
    const int t = threadIdx.x;
    long rowBase, colBase;
    swizzle_blk(blockIdx.x, rowBase, colBase);

    GEMM_CORE(A, B, As, Bs)

#pragma unroll
    for (int mi = 0; mi < 4; ++mi) {
#pragma unroll
        for (int ni = 0; ni < 4; ++ni) {
            long col = colBase + wc * 64 + ni * 16 + c16;
            long row0 = rowBase + wr * 64 + mi * 16 + q * 4;
#pragma unroll
            for (int r = 0; r < 4; ++r)
                C[(row0 + r) * 1024 + col] = f2bf(acc[mi][ni][r]);
        }
    }
}

// ---------------------------------------------------------------------------
// LayerNorm over D=1024: y = ypre + out_b + x; out = (y-mu)/sqrt(var+eps)*g+b
__global__ __launch_bounds__(256) void ln_k(const unsigned short* __restrict__ ypre,
                                            const float* __restrict__ x,
                                            const float* __restrict__ outb,
                                            const float* __restrict__ gam,
                                            const float* __restrict__ bet,
                                            float* __restrict__ out) {
    int row = blockIdx.x;       // 16384
    int t = threadIdx.x;        // 256, 4 elems each
    long base = (long)row * 1024 + t * 4;
    ushort4 yp = *(const ushort4*)(ypre + base);
    float4 xv = *(const float4*)(x + base);
    float4 bv = *(const float4*)(outb + t * 4);
    float y0 = bf2f(yp.x) + xv.x + bv.x;
    float y1 = bf2f(yp.y) + xv.y + bv.y;
    float y2 = bf2f(yp.z) + xv.z + bv.z;
    float y3 = bf2f(yp.w) + xv.w + bv.w;
    float s = y0 + y1 + y2 + y3;
    float ss = y0 * y0 + y1 * y1 + y2 * y2 + y3 * y3;
    for (int off = 32; off; off >>= 1) {
        s += __shfl_down(s, off);
        ss += __shfl_down(ss, off);
    }
    __shared__ float red[8];
    int wv = t >> 6, ln = t & 63;
    if (ln == 0) { red[wv] = s; red[4 + wv] = ss; }
    __syncthreads();
    float S1 = red[0] + red[1] + red[2] + red[3];
    float S2 = red[4] + red[5] + red[6] + red[7];
    float mu = S1 * (1.0f / 1024.0f);
    float var = S2 * (1.0f / 1024.0f) - mu * mu;
    float rs = 1.0f / sqrtf(var + 1e-5f);
    float4 gv = *(const float4*)(gam + t * 4);
    float4 bb = *(const float4*)(bet + t * 4);
    float4 o;
    o.x = (y0 - mu) * rs * gv.x + bb.x;
    o.y = (y1 - mu) * rs * gv.y + bb.y;
    o.z = (y2 - mu) * rs * gv.z + bb.z;
    o.w = (y3 - mu) * rs * gv.w + bb.w;
    *(float4*)(out + base) = o;
}

// ---------------------------------------------------------------------------
extern "C" void kernel_launch(void* const* d_in, const int* in_sizes, int n_in,
                              void* d_out, int out_size, void* d_ws, size_t ws_size,
                              hipStream_t stream) {
    const float* x       = (const float*)d_in[0];
    const float* W_proj  = (const float*)d_in[1];
    const float* freqs   = (const float*)d_in[2];
    const float* pol_W   = (const float*)d_in[3];
    const float* pol_b   = (const float*)d_in[4];
    const float* imp_W1  = (const float*)d_in[5];
    const float* imp_b1  = (const float*)d_in[6];
    const float* imp_W2  = (const float*)d_in[7];
    const float* imp_b2  = (const float*)d_in[8];
    const float* out_W   = (const float*)d_in[9];
    const float* out_b   = (const float*)d_in[10];
    const float* ln_g    = (const float*)d_in[11];
    const float* ln_b    = (const float*)d_in[12];
    const int*   causal  = (const int*)d_in[13];
    float* out = (float*)d_out;

    char* ws = (char*)d_ws;
    unsigned short* xb      = (unsigned short*)(ws + 0);          // 32MB, dead after gemm1 -> reused as ypre
    unsigned short* merged  = (unsigned short*)(ws + 33554432);   // 32MB
    unsigned short* w1b     = (unsigned short*)(ws + 67108864);   // 2MB
    unsigned short* wob     = (unsigned short*)(ws + 69206016);   // 2MB
    float* xbar             = (float*)(ws + 71303168);            // 16KB
    float* summary          = (float*)(ws + 71319552);            // 16KB
    float* coef             = (float*)(ws + 71335936);            // 1KB
    float* part             = (float*)merged;                     // 4MB, dead before gemm1_mix writes merged
    unsigned short* ypre    = xb;

    prep_k<<<8192, 256, 0, stream>>>(W_proj, freqs, out_W, w1b, wob);
    xbar_cast<<<1024, 256, 0, stream>>>(x, xb, part);
    xbar_r<<<32, 256, 0, stream>>>(part, xbar);
    summary_k<<<1024, 256, 0, stream>>>(xbar, W_proj, freqs, summary);
    imp_k<<<1, 256, 0, stream>>>(summary, pol_W, pol_b, imp_W1, imp_b1,
                                 imp_W2, imp_b2, coef, out + 16777216);
    gemm1_mix<<<1024, 256, 0, stream>>>(xb, w1b, coef, causal, merged);
    gemm_bt<<<1024, 256, 0, stream>>>(merged, wob, ypre);
    ln_k<<<16384, 256, 0, stream>>>(ypre, x, out_b, ln_g, ln_b, out);
}